// Round 12
// baseline (596.376 us; speedup 1.0000x reference)
//
#include <hip/hip_runtime.h>
#include <math.h>

#define D_MODEL 1024
#define D_STATE 32
#define D_CONV  4
#define D_INNER 2048
#define DT_RANK 64
#define BATCH   4
#define SEQ     2048
#define NTOK    (BATCH*SEQ)            // 8192 rows
#define DBC_N   (DT_RANK + 2*D_STATE)  // 128
#define NC      64                     // scan chunks
#define CL      (SEQ/NC)               // 32 steps per chunk
#define KSPLIT  4                      // split-K factor for dbc GEMM
#define LOG2E   1.4426950408889634f

typedef unsigned short u16;
typedef short bf16x8 __attribute__((ext_vector_type(8)));
typedef float f32x4  __attribute__((ext_vector_type(4)));
typedef u16   u16x8  __attribute__((ext_vector_type(8)));

__device__ __forceinline__ float bf2f(u16 u){
  return __uint_as_float(((unsigned)u) << 16);
}
__device__ __forceinline__ u16 f2bf(float f){   // round-to-nearest-even
  unsigned u = __float_as_uint(f);
  return (u16)((u + 0x7fffu + ((u >> 16) & 1u)) >> 16);
}
__device__ __forceinline__ float sigmoidf_(float x){ return 1.f/(1.f+__expf(-x)); }
// raw v_exp_f32: r = 2^x (1 instruction; __expf = mul + this)
__device__ __forceinline__ float exp2_fast(float x){
  float r;
  asm("v_exp_f32 %0, %1" : "=v"(r) : "v"(x));
  return r;
}

typedef __attribute__((address_space(3))) void       lds_v;
typedef const __attribute__((address_space(1))) void gl_v;
#define GLOAD_LDS16(g, l) \
  __builtin_amdgcn_global_load_lds((gl_v*)(g), (lds_v*)(l), 16, 0, 0)

// ---------------------------------------------------------------------------
// bf16 MFMA GEMM: C = A[M,K] @ W[K,N], A bf16 row-major [M][K], B = weight
// PRE-TRANSPOSED bf16 [N][K]. 128x128 tile, BK=64, 4 waves of 64x64.
// Staging via global_load_lds width=16 into LINEAR [128][64] LDS (32 KB).
// SWIZZLE (both-sides-or-neither): LDS[r][c'] holds logical 16B chunk
// c = c' ^ (r&7); staging fetches global chunk c_d ^ (r&7); reads XOR the
// same key -> all 8 bank-quads hit 2x per 16-lane group (2-way = free).
// ~810 TF on in_proj = at the m97-structure ceiling.
// Only used for K >= 512 shapes (K=64 delta GEMM is latency-bound here).
// MODES:
//  0: f32 store C1[row*ldc+col]                       (out_proj)
//  2: split in_proj, BOTH bf16: col<D_INNER -> (u16*)C1; else C2@col-2048
//  3: split-K partials: K arg = Kc; A,B advanced by kz*Kc;
//     store f32 at C1 + kz*NTOK*DBC_N                  (dbc)
// ---------------------------------------------------------------------------
template<int MODE>
__global__ __launch_bounds__(256)
void mfma_gemm(int K,
               const u16* __restrict__ A, int lda,
               const u16* __restrict__ B, int ldb,   // [N][K]
               void* __restrict__ C1, int ldc,
               u16*  __restrict__ C2)
{
  __shared__ u16 As[128*64];
  __shared__ u16 Bs[128*64];
  const int tid  = threadIdx.x;
  const int lane = tid & 63;
  const int wave = tid >> 6;
  const int wm = (wave>>1)*64, wn = (wave&1)*64;
  const int m0 = blockIdx.y*128, n0 = blockIdx.x*128;
  const size_t koff = (MODE==3) ? (size_t)blockIdx.z*K : 0;

  // staging: 4 gloads/tile; gload g covers rows 32g..32g+31.
  const int srow = tid >> 3;            // 0..31 row within 32-row group
  const int sch  = ((tid & 7) ^ (srow & 7)) * 8;   // swizzled source chunk

  const u16* Ag = A + (size_t)(m0 + srow)*lda + sch + koff;
  const u16* Bg = B + (size_t)(n0 + srow)*ldb + sch + koff;

  const int fr = lane & 15;         // fragment row within 16
  const int fq = lane >> 4;         // quad: k-chunk of 8
  const int rkey = (fr & 7);        // read-side XOR key (loop-invariant)
  f32x4 acc[4][4] = {};

  for (int k0=0; k0<K; k0+=64){
    #pragma unroll
    for (int g=0; g<4; ++g){
      GLOAD_LDS16(Ag + (size_t)(32*g)*lda + k0, &As[g*2048 + tid*8]);
      GLOAD_LDS16(Bg + (size_t)(32*g)*ldb + k0, &Bs[g*2048 + tid*8]);
    }
    __syncthreads();                 // drains vmcnt -> LDS tile ready

    #pragma unroll
    for (int ks=0; ks<2; ++ks){
      const int rc = ((ks*4 + fq) ^ rkey) * 8;   // swizzled read chunk
      bf16x8 af[4], bfr[4];
      #pragma unroll
      for (int i=0;i<4;i++){
        af[i]  = *(const bf16x8*)&As[(wm + i*16 + fr)*64 + rc];
        bfr[i] = *(const bf16x8*)&Bs[(wn + i*16 + fr)*64 + rc];
      }
      #pragma unroll
      for (int mi=0;mi<4;mi++)
        #pragma unroll
        for (int ni=0;ni<4;ni++)
          acc[mi][ni] = __builtin_amdgcn_mfma_f32_16x16x32_bf16(
              af[mi], bfr[ni], acc[mi][ni], 0, 0, 0);
    }
    __syncthreads();                 // all reads done before next overwrite
  }

  float* Cf = (float*)C1;
  if (MODE==3) Cf += (size_t)blockIdx.z*((size_t)NTOK*DBC_N);

  // C/D layout: row = fq*4 + r, col = fr  (m89-verified)
  const bool second = (MODE==2) && (n0 >= D_INNER);   // block-uniform
  #pragma unroll
  for (int mi=0;mi<4;mi++){
    #pragma unroll
    for (int ni=0;ni<4;ni++){
      int col = n0 + wn + ni*16 + fr;
      #pragma unroll
      for (int r=0;r<4;r++){
        int row = m0 + wm + mi*16 + fq*4 + r;
        float v = acc[mi][ni][r];
        if (MODE==0 || MODE==3){
          Cf[(size_t)row*ldc + col] = v;
        } else {  // MODE 2: dual bf16
          if (second) C2[(size_t)row*D_INNER + (col - D_INNER)] = f2bf(v);
          else        ((u16*)C1)[(size_t)row*D_INNER + col]     = f2bf(v);
        }
      }
    }
  }
}

// ---------------------------------------------------------------------------
// delta = softplus(dbc[:, :64] @ dt_proj_w + bias) -> bf16.
// f32 vector-ALU GEMM. R11 post-mortem: with TM=TN=4 the kernel is
// LDS-BANDWIDTH-bound (every element re-read 16x: 134M ds_read_b128 x
// ~12cyc ~ 82us, matching the 90-92us measured; barriers/conflicts were
// red herrings). Fix: 128x128 tile, TM=TN=8 -> 4 b128 per 64 FMA (2x less
// LDS traffic), conflict-free layouts:
//  - As[64][128] (k-major): ra reads are 16-lane broadcasts at 4 distinct
//    banks; transposed staging stores are 2-way (free).
//  - Bs stored as f4-permuted [64][32]: phys(g) = (g&1)*16 + (g>>1), so
//    per-kk rb reads land on consecutive 16B slots across tcol (2-way).
// Output: one 16B u16x8 store per row. LDS 64KB -> 2 blocks/CU (fine:
// throughput-bound with 64-wide FMA ILP per kk).
// ---------------------------------------------------------------------------
__global__ __launch_bounds__(256)
void sgemm_softplus(const float* __restrict__ A, int lda,   // dbc [NTOK][128]
                    const float* __restrict__ B, int ldb,   // dt_proj_w [64][2048]
                    u16* __restrict__ C, int ldc,           // delta_bf
                    const float* __restrict__ bias)
{
  __shared__ float As[DT_RANK][128];       // [k][m]
  __shared__ f32x4 Bs[DT_RANK][32];        // [k][phys f4]
  const int tid  = threadIdx.x;
  const int brow = blockIdx.y, bcol = blockIdx.x;

  const float* Ag = A + (size_t)brow*128*lda;
  const float* Bg = B + (size_t)bcol*128;

  // A stage: thread t covers row m = t>>1, k-half kh = (t&1)*32 (32 f32).
  {
    const int m  = tid >> 1;
    const int kh = (tid & 1)*32;
    const float* src = Ag + (size_t)m*lda + kh;
    #pragma unroll
    for (int j=0; j<8; ++j){
      float4 av = *(const float4*)(src + 4*j);
      As[kh+4*j+0][m]=av.x; As[kh+4*j+1][m]=av.y;
      As[kh+4*j+2][m]=av.z; As[kh+4*j+3][m]=av.w;
    }
  }
  // B stage: thread t covers row r = t>>2, f4 group cg = (t&3)*8 (8 f4s),
  // stored permuted: phys(g) = (g&1)*16 + (g>>1).
  {
    const int r  = tid >> 2;
    const int cg = (tid & 3)*8;
    const float* src = Bg + (size_t)r*ldb + cg*4;
    #pragma unroll
    for (int j=0; j<8; ++j){
      int g = cg + j;
      float4 bv = *(const float4*)(src + 4*j);
      Bs[r][(g&1)*16 + (g>>1)] = *(f32x4*)&bv;
    }
  }
  __syncthreads();

  const int trow = tid >> 4;           // 0..15: rows trow*8..+7
  const int tcol = tid & 15;           // 0..15: cols tcol*8..+7

  float acc[8][8] = {};
  #pragma unroll 4
  for (int kk=0; kk<DT_RANK; ++kk){
    f32x4 ra0 = *(const f32x4*)&As[kk][trow*8];
    f32x4 ra1 = *(const f32x4*)&As[kk][trow*8+4];
    f32x4 rb0 = Bs[kk][tcol];          // logical cols tcol*8 + 0..3
    f32x4 rb1 = Bs[kk][16+tcol];       // logical cols tcol*8 + 4..7
    float ra[8] = {ra0[0],ra0[1],ra0[2],ra0[3],ra1[0],ra1[1],ra1[2],ra1[3]};
    float rb[8] = {rb0[0],rb0[1],rb0[2],rb0[3],rb1[0],rb1[1],rb1[2],rb1[3]};
    #pragma unroll
    for (int m=0;m<8;m++)
      #pragma unroll
      for (int n=0;n<8;n++)
        acc[m][n] += ra[m]*rb[n];
  }

  float bs[8];
  #pragma unroll
  for (int n=0;n<8;n++) bs[n] = bias[bcol*128 + tcol*8 + n];

  #pragma unroll
  for (int m=0;m<8;m++){
    int row = brow*128 + trow*8 + m;
    u16x8 o;
    #pragma unroll
    for (int n=0;n<8;n++){
      float v = acc[m][n] + bs[n];
      v = (v > 20.f) ? v : log1pf(__expf(v));
      o[n] = f2bf(v);
    }
    *(u16x8*)(C + (size_t)row*ldc + bcol*128 + tcol*8) = o;
  }
}

// ---------------------------------------------------------------------------
// f32 -> bf16 elementwise (n multiple of 1024)
// ---------------------------------------------------------------------------
__global__ __launch_bounds__(256)
void cvt_f32_bf16(const float* __restrict__ in, u16* __restrict__ out)
{
  size_t i = (size_t)blockIdx.x*256 + threadIdx.x;
  float4 v = ((const float4*)in)[i];
  ushort4 o;
  o.x=f2bf(v.x); o.y=f2bf(v.y); o.z=f2bf(v.z); o.w=f2bf(v.w);
  ((ushort4*)out)[i] = o;
}

// ---------------------------------------------------------------------------
// f32 [R][C] -> bf16 [C][R] transpose+convert, 64x64 tiles, 256 threads.
// ---------------------------------------------------------------------------
__global__ __launch_bounds__(256)
void transpose_cvt(const float* __restrict__ in, u16* __restrict__ out,
                   int R, int C)
{
  __shared__ float tile[64][65];
  const int bc = blockIdx.x*64, br = blockIdx.y*64;
  const int tx = threadIdx.x & 63, ty = threadIdx.x >> 6;
  #pragma unroll
  for (int i=0;i<16;i++){
    int r = ty + i*4;
    tile[r][tx] = in[(size_t)(br+r)*C + bc+tx];
  }
  __syncthreads();
  #pragma unroll
  for (int i=0;i<16;i++){
    int r = ty + i*4;
    out[(size_t)(bc+r)*R + br+tx] = f2bf(tile[tx][r]);
  }
}

// ---------------------------------------------------------------------------
// reduce KSPLIT partials into dbc (float4-vectorized over NTOK*DBC_N).
// ---------------------------------------------------------------------------
__global__ __launch_bounds__(256)
void reduce_pk(const float* __restrict__ part, float* __restrict__ dbc)
{
  size_t i = (size_t)blockIdx.x*256 + threadIdx.x;   // float4 index
  const size_t stride4 = (size_t)NTOK*DBC_N/4;
  float4 s = ((const float4*)part)[i];
  #pragma unroll
  for (int z=1; z<KSPLIT; ++z){
    float4 v = ((const float4*)part)[z*stride4 + i];
    s.x+=v.x; s.y+=v.y; s.z+=v.z; s.w+=v.w;
  }
  ((float4*)dbc)[i] = s;
}

// ---------------------------------------------------------------------------
// Depthwise causal conv (K=4) + bias + SiLU. bf16 in -> bf16 out (u).
// Vectorized: each thread handles 8 consecutive channels (ushort8 loads).
// ---------------------------------------------------------------------------
__global__ __launch_bounds__(256)
void conv_silu_kernel(const u16* __restrict__ xi_bf,
                      const float* __restrict__ conv_w,
                      const float* __restrict__ conv_b,
                      u16* __restrict__ u_bf)
{
  size_t i8 = (size_t)blockIdx.x*256 + threadIdx.x;  // over NTOK*D_INNER/8
  size_t base = i8*8;
  int d0 = (int)(base % D_INNER);
  size_t bt = base / D_INNER;
  int t = (int)(bt % SEQ);
  size_t b = bt / SEQ;
  const u16* xi = xi_bf + b*(size_t)SEQ*D_INNER + d0;

  float accv[8];
  #pragma unroll
  for (int j=0;j<8;j++) accv[j] = conv_b[d0+j];
  float4 cw[8];
  #pragma unroll
  for (int j=0;j<8;j++) cw[j] = *(const float4*)(conv_w + (size_t)(d0+j)*D_CONV);

  #pragma unroll
  for (int k=0;k<D_CONV;k++){
    int tt = t + k - (D_CONV-1);
    if (tt >= 0){
      u16x8 v = *(const u16x8*)(xi + (size_t)tt*D_INNER);
      accv[0] += bf2f(v[0]) * ((const float*)&cw[0])[k];
      accv[1] += bf2f(v[1]) * ((const float*)&cw[1])[k];
      accv[2] += bf2f(v[2]) * ((const float*)&cw[2])[k];
      accv[3] += bf2f(v[3]) * ((const float*)&cw[3])[k];
      accv[4] += bf2f(v[4]) * ((const float*)&cw[4])[k];
      accv[5] += bf2f(v[5]) * ((const float*)&cw[5])[k];
      accv[6] += bf2f(v[6]) * ((const float*)&cw[6])[k];
      accv[7] += bf2f(v[7]) * ((const float*)&cw[7])[k];
    }
  }
  u16x8 o;
  #pragma unroll
  for (int j=0;j<8;j++){
    float r = accv[j] * sigmoidf_(accv[j]);
    o[j] = f2bf(r);
  }
  *(u16x8*)(u_bf + base) = o;
}

// ---------------------------------------------------------------------------
// Chunked selective scan, pass 1: lane = channel, h[32] in registers.
// (Full-state, NC=64, plain global B reads — R8's LDS staging was neutral-
// negative: kernel is ~17% HBM, redundant loads were free L1 broadcasts.)
// FAST PATH (runtime-verified): A_log = log(tile(arange(1..32))) ->
// A2[s] = A2[0]*(s+1), so exp(dl*A[s]) = E^(s+1): ONE v_exp per timestep.
// delta/u are bf16.
// ---------------------------------------------------------------------------
__global__ __launch_bounds__(256)
void scan_part1(const float* __restrict__ dbc,     // (NTOK,128)
                const u16*   __restrict__ delta,   // (NTOK,D_INNER) bf16
                const u16*   __restrict__ u,       // (NTOK,D_INNER) bf16
                const float* __restrict__ A_log,   // (D_INNER,32)
                float* __restrict__ q,             // (B,NC,D_INNER,32)
                float* __restrict__ sumdl_buf)     // (B,NC,D_INNER)
{
  const int ndg  = D_INNER/256;                 // 8
  const int dgrp = blockIdx.x % ndg;
  const int c    = (blockIdx.x / ndg) % NC;
  const int b    =  blockIdx.x / (ndg*NC);
  const int d    = dgrp*256 + threadIdx.x;

  const float* Ap = A_log + (size_t)d*D_STATE;
  const float base = -__expf(Ap[0]) * LOG2E;      // log2e folded into A
  bool fastp = true;
  #pragma unroll
  for (int s=1; s<D_STATE; ++s){
    float a2 = -__expf(Ap[s]) * LOG2E;
    float ideal = base * (float)(s+1);
    fastp = fastp && (fabsf(a2 - ideal) <= 1e-4f*fabsf(ideal));
  }

  const size_t tok0 = (size_t)b*SEQ + (size_t)c*CL;
  const u16*   dptr = delta + tok0*D_INNER + d;
  const u16*   uptr = u     + tok0*D_INNER + d;
  const float* dbcp = dbc   + tok0*DBC_N;

  float h[D_STATE] = {};
  float sumdl = 0.f;

  if (fastp){
    for (int t=0; t<CL; ++t){
      float dl = bf2f(dptr[(size_t)t*D_INNER]);
      float uu = bf2f(uptr[(size_t)t*D_INNER]);
      sumdl += dl;
      float w  = dl*uu;
      float E  = exp2_fast(dl*base);
      float E2 = E*E, E3 = E2*E, E4 = E2*E2;
      float P  = 1.f;
      const float4* B4 = (const float4*)(dbcp + (size_t)t*DBC_N + DT_RANK);
      #pragma unroll
      for (int g=0; g<8; ++g){
        float4 Bv = B4[g];
        float m0 = P*E, m1 = P*E2, m2 = P*E3, m3 = P*E4;
        h[4*g+0] = m0*h[4*g+0] + w*Bv.x;
        h[4*g+1] = m1*h[4*g+1] + w*Bv.y;
        h[4*g+2] = m2*h[4*g+2] + w*Bv.z;
        h[4*g+3] = m3*h[4*g+3] + w*Bv.w;
        P = m3;
      }
    }
  } else {
    float A2[D_STATE];
    #pragma unroll
    for (int g=0; g<8; ++g){
      float4 al = *(const float4*)(Ap + 4*g);
      A2[4*g+0] = -__expf(al.x)*LOG2E; A2[4*g+1] = -__expf(al.y)*LOG2E;
      A2[4*g+2] = -__expf(al.z)*LOG2E; A2[4*g+3] = -__expf(al.w)*LOG2E;
    }
    for (int t=0; t<CL; ++t){
      float dl = bf2f(dptr[(size_t)t*D_INNER]);
      float uu = bf2f(uptr[(size_t)t*D_INNER]);
      sumdl += dl;
      float w = dl*uu;
      const float4* B4 = (const float4*)(dbcp + (size_t)t*DBC_N + DT_RANK);
      #pragma unroll
      for (int g=0; g<8; ++g){
        float4 Bv = B4[g];
        h[4*g+0] = exp2_fast(dl*A2[4*g+0])*h[4*g+0] + w*Bv.x;
        h[4*g+1] = exp2_fast(dl*A2[4*g+1])*h[4*g+1] + w*Bv.y;
        h[4*g+2] = exp2_fast(dl*A2[4*g+2])*h[4*g+2] + w*Bv.z;
        h[4*g+3] = exp2_fast(dl*A2[4*g+3])*h[4*g+3] + w*Bv.w;
      }
    }
  }

  float* qp = q + (((size_t)b*NC + c)*D_INNER + d)*D_STATE;
  #pragma unroll
  for (int g=0; g<8; ++g)
    ((float4*)qp)[g] = make_float4(h[4*g+0],h[4*g+1],h[4*g+2],h[4*g+3]);
  sumdl_buf[((size_t)b*NC + c)*D_INNER + d] = sumdl;
}

// ---------------------------------------------------------------------------
// Pass 2: sequential combine across chunks, in-place on q.
// ---------------------------------------------------------------------------
__global__ __launch_bounds__(256)
void scan_combine(float* __restrict__ q,
                  const float* __restrict__ sumdl_buf,
                  const float* __restrict__ A_log)
{
  size_t idx = (size_t)blockIdx.x*256 + threadIdx.x;   // over B*D_INNER*32
  int s = (int)(idx % D_STATE);
  size_t dd = idx / D_STATE;
  int d = (int)(dd % D_INNER);
  int b = (int)(dd / D_INNER);

  const float As2 = -__expf(A_log[(size_t)d*D_STATE + s]) * LOG2E;
  float H = 0.f;
  for (int c=0; c<NC; ++c){
    size_t off = (((size_t)b*NC + c)*D_INNER + d)*D_STATE + s;
    float tmp = q[off];          // chunk-local end state
    q[off] = H;                  // h_in for chunk c
    H = exp2_fast(As2 * sumdl_buf[((size_t)b*NC + c)*D_INNER + d]) * H + tmp;
  }
}

// ---------------------------------------------------------------------------
// Pass 3: re-run recurrence from h_in; y = sum_s h*C, fused D-skip + z-gate.
// y accumulated in FOUR independent partials (chain depth 32 -> 10; the
// compiler cannot reassociate without fast-math).
// z bf16 read, y bf16 written IN-PLACE (same slot, same thread -> race-free).
// ---------------------------------------------------------------------------
__global__ __launch_bounds__(256)
void scan_part2(const float* __restrict__ dbc,     // (NTOK,128)
                const u16*   __restrict__ delta,   // (NTOK,D_INNER) bf16
                const u16*   __restrict__ u,       // bf16
                u16*         __restrict__ zy,      // in: z bf16, out: y bf16
                const float* __restrict__ q,       // h_in per chunk
                const float* __restrict__ A_log,
                const float* __restrict__ Dp)
{
  const int ndg  = D_INNER/256;
  const int dgrp = blockIdx.x % ndg;
  const int c    = (blockIdx.x / ndg) % NC;
  const int b    =  blockIdx.x / (ndg*NC);
  const int d    = dgrp*256 + threadIdx.x;

  const float* Ap = A_log + (size_t)d*D_STATE;
  const float base = -__expf(Ap[0]) * LOG2E;
  bool fastp = true;
  #pragma unroll
  for (int s=1; s<D_STATE; ++s){
    float a2 = -__expf(Ap[s]) * LOG2E;
    float ideal = base * (float)(s+1);
    fastp = fastp && (fabsf(a2 - ideal) <= 1e-4f*fabsf(ideal));
  }

  float h[D_STATE];
  const float* qp = q + (((size_t)b*NC + c)*D_INNER + d)*D_STATE;
  #pragma unroll
  for (int g=0; g<8; ++g){
    float4 hv = ((const float4*)qp)[g];
    h[4*g+0]=hv.x; h[4*g+1]=hv.y; h[4*g+2]=hv.z; h[4*g+3]=hv.w;
  }
  const float Dd = Dp[d];

  const size_t tok0 = (size_t)b*SEQ + (size_t)c*CL;
  const u16*   dptr = delta + tok0*D_INNER + d;
  const u16*   uptr = u     + tok0*D_INNER + d;
  u16*         zp   = zy    + tok0*D_INNER + d;
  const float* dbcp = dbc   + tok0*DBC_N;

  if (fastp){
    for (int t=0; t<CL; ++t){
      float dl = bf2f(dptr[(size_t)t*D_INNER]);
      float uu = bf2f(uptr[(size_t)t*D_INNER]);
      float zz = bf2f(zp[(size_t)t*D_INNER]);
      float w  = dl*uu;
      float E  = exp2_fast(dl*base);
      float E2 = E*E, E3 = E2*E, E4 = E2*E2;
      float P  = 1.f;
      const float4* B4 = (const float4*)(dbcp + (size_t)t*DBC_N + DT_RANK);
      const float4* C4 = B4 + 8;
      float ya0 = 0.f, ya1 = 0.f, ya2 = 0.f, ya3 = 0.f;
      #pragma unroll
      for (int g=0; g<8; ++g){
        float4 Bv = B4[g];
        float4 Cv = C4[g];
        float m0 = P*E, m1 = P*E2, m2 = P*E3, m3 = P*E4;
        h[4*g+0] = m0*h[4*g+0] + w*Bv.x;  ya0 += h[4*g+0]*Cv.x;
        h[4*g+1] = m1*h[4*g+1] + w*Bv.y;  ya1 += h[4*g+1]*Cv.y;
        h[4*g+2] = m2*h[4*g+2] + w*Bv.z;  ya2 += h[4*g+2]*Cv.z;
        h[4*g+3] = m3*h[4*g+3] + w*Bv.w;  ya3 += h[4*g+3]*Cv.w;
        P = m3;
      }
      float y = (ya0 + ya1) + (ya2 + ya3);
      zp[(size_t)t*D_INNER] = f2bf((y + uu*Dd) * (zz * sigmoidf_(zz)));
    }
  } else {
    float A2[D_STATE];
    #pragma unroll
    for (int g=0; g<8; ++g){
      float4 al = *(const float4*)(Ap + 4*g);
      A2[4*g+0] = -__expf(al.x)*LOG2E; A2[4*g+1] = -__expf(al.y)*LOG2E;
      A2[4*g+2] = -__expf(al.z)*LOG2E; A2[4*g+3] = -__expf(al.w)*LOG2E;
    }
    for (int t=0; t<CL; ++t){
      float dl = bf2f(dptr[(size_t)t*D_INNER]);
      float uu = bf2f(uptr[(size_t)t*D_INNER]);
      float zz = bf2f(zp[(size_t)t*D_INNER]);
      float w  = dl*uu;
      const float4* B4 = (const float4*)(dbcp + (size_t)t*DBC_N + DT_RANK);
      const float4* C4 = B4 + 8;
      float ya0 = 0.f, ya1 = 0.f, ya2 = 0.f, ya3 = 0.f;
      #pragma unroll
      for (int g=0; g<8; ++g){
        float4 Bv = B4[g];
        float4 Cv = C4[g];
        h[4*g+0] = exp2_fast(dl*A2[4*g+0])*h[4*g+0] + w*Bv.x;  ya0 += h[4*g+0]*Cv.x;
        h[4*g+1] = exp2_fast(dl*A2[4*g+1])*h[4*g+1] + w*Bv.y;  ya1 += h[4*g+1]*Cv.y;
        h[4*g+2] = exp2_fast(dl*A2[4*g+2])*h[4*g+2] + w*Bv.z;  ya2 += h[4*g+2]*Cv.z;
        h[4*g+3] = exp2_fast(dl*A2[4*g+3])*h[4*g+3] + w*Bv.w;  ya3 += h[4*g+3]*Cv.w;
      }
      float y = (ya0 + ya1) + (ya2 + ya3);
      zp[(size_t)t*D_INNER] = f2bf((y + uu*Dd) * (zz * sigmoidf_(zz)));
    }
  }
}

// ---------------------------------------------------------------------------
// LayerNorm over last dim (1024): read f32 pre-LN, write f32 output.
// float4 loads/stores: thread t owns cols [4t, 4t+4).
// ---------------------------------------------------------------------------
__global__ __launch_bounds__(256)
void ln_kernel(const float* __restrict__ in,
               float* __restrict__ out,
               const float* __restrict__ gamma,
               const float* __restrict__ beta)
{
  const int row = blockIdx.x;
  const float* p = in + (size_t)row*D_MODEL;
  float* q = out + (size_t)row*D_MODEL;
  float4 v = ((const float4*)p)[threadIdx.x];
  float s  = v.x+v.y+v.z+v.w;
  float ss = v.x*v.x+v.y*v.y+v.z*v.z+v.w*v.w;
  #pragma unroll
  for (int off=32; off; off>>=1){
    s  += __shfl_xor(s,  off, 64);
    ss += __shfl_xor(ss, off, 64);
  }
  __shared__ float sw[4], ssw[4];
  const int wid = threadIdx.x >> 6;
  if ((threadIdx.x & 63) == 0){ sw[wid]=s; ssw[wid]=ss; }
  __syncthreads();
  s  = sw[0]+sw[1]+sw[2]+sw[3];
  ss = ssw[0]+ssw[1]+ssw[2]+ssw[3];
  const float mu  = s * (1.f/D_MODEL);
  const float var = ss * (1.f/D_MODEL) - mu*mu;
  const float inv = rsqrtf(var + 1e-5f);
  float4 gm = ((const float4*)gamma)[threadIdx.x];
  float4 bt = ((const float4*)beta )[threadIdx.x];
  float4 o;
  o.x = (v.x-mu)*inv*gm.x + bt.x;
  o.y = (v.y-mu)*inv*gm.y + bt.y;
  o.z = (v.z-mu)*inv*gm.z + bt.z;
  o.w = (v.w-mu)*inv*gm.w + bt.w;
  ((float4*)q)[threadIdx.x] = o;
}

// ---------------------------------------------------------------------------
extern "C" void kernel_launch(void* const* d_in, const int* in_sizes, int n_in,
                              void* d_out, int out_size, void* d_ws, size_t ws_size,
                              hipStream_t stream)
{
  const float* x          = (const float*)d_in[0];   // (4,2048,1024) f32
  const float* in_proj_w  = (const float*)d_in[1];   // (1024,4096)
  const float* conv_w     = (const float*)d_in[2];   // (2048,4)
  const float* conv_b     = (const float*)d_in[3];   // (2048,)
  const float* x_proj_w   = (const float*)d_in[4];   // (2048,128)
  const float* dt_proj_w  = (const float*)d_in[5];   // (64,2048)
  const float* dt_proj_b  = (const float*)d_in[6];   // (2048,)
  const float* A_log      = (const float*)d_in[7];   // (2048,32)
  const float* Dp         = (const float*)d_in[8];   // (2048,)
  const float* out_proj_w = (const float*)d_in[9];   // (2048,1024)
  const float* ln_gamma   = (const float*)d_in[10];  // (1024,)
  const float* ln_beta    = (const float*)d_in[11];  // (1024,)
  float* out = (float*)d_out;                        // (4,2048,1024) f32 OUTPUT

  // workspace (byte offsets), ws_size = 256 MiB:
  //   @0     x_bf bf16 16M (steps 0-1) -> pkpart f32 16M (step 3)
  //          -> qbuf f32 64M (step 5, covers 0-64M; pkpart+xi_bf dead)
  //          -> preln f32 32M (steps 6-7; qbuf dead)
  //   @32M   xi_bf bf16 32M (steps 1-2)
  //   @64M   u_bf bf16 32M (steps 2,3,5)
  //   @96M   zybuf bf16 32M (steps 1,5,6)
  //   @128M  delta_bf bf16 32M (steps 4,5)
  //   @160M  dbc f32 4M ; @165M sumdl 2M (NC=64)
  //   @198M  w_inT 8M ; @206M w_outT 4M ; @210M x_projT
  char* ws = (char*)d_ws;
  u16*   x_bf    = (u16*)  (ws + 0);
  float* pkpart  = (float*)(ws + 0);
  float* qbuf    = (float*)(ws + 0);
  float* preln   = (float*)(ws + 0);
  u16*   xi_bf   = (u16*)  (ws + (size_t) 33554432);
  u16*   u_bf    = (u16*)  (ws + (size_t) 67108864);
  u16*   zybuf   = (u16*)  (ws + (size_t)100663296);
  u16*   delta_bf= (u16*)  (ws + (size_t)134217728);
  float* dbc     = (float*)(ws + (size_t)167772160);
  float* sumdl   = (float*)(ws + (size_t)173015040);
  u16*   w_inT   = (u16*)  (ws + (size_t)207618048);
  u16*   w_outT  = (u16*)  (ws + (size_t)216006656);
  u16*   x_projT = (u16*)  (ws + (size_t)220200960);

  // 0) dtype prep: x -> bf16; weights -> bf16 transposed [N][K]
  cvt_f32_bf16<<<(NTOK*(size_t)D_MODEL)/1024, 256, 0, stream>>>(x, x_bf);
  { dim3 g(4096/64, 1024/64); transpose_cvt<<<g,256,0,stream>>>(in_proj_w,  w_inT,  1024, 4096); }
  { dim3 g(1024/64, 2048/64); transpose_cvt<<<g,256,0,stream>>>(out_proj_w, w_outT, 2048, 1024); }
  { dim3 g( 128/64, 2048/64); transpose_cvt<<<g,256,0,stream>>>(x_proj_w,   x_projT, 2048, 128); }

  // 1) merged in_proj: [xi | z] = x @ in_proj_w  (MFMA, dual bf16 epilogue)
  {
    dim3 grid(2*D_INNER/128, NTOK/128);
    mfma_gemm<2><<<grid,256,0,stream>>>(D_MODEL,
        x_bf, D_MODEL, w_inT, D_MODEL, xi_bf, 0, zybuf);
  }
  // 2) u = silu(conv(xi) + conv_b)   bf16 -> bf16  (xi_bf dead after)
  conv_silu_kernel<<<(NTOK*(size_t)D_INNER)/2048,256,0,stream>>>(
      xi_bf, conv_w, conv_b, u_bf);

  // 3) dbc = u_bf @ x_proj_w  (MFMA split-K over 4, partials @0, x_bf dead)
  {
    dim3 grid(DBC_N/128, NTOK/128, KSPLIT);     // (1,64,4)
    mfma_gemm<3><<<grid,256,0,stream>>>(D_INNER/KSPLIT,
        u_bf, D_INNER, x_projT, D_INNER, pkpart, DBC_N, nullptr);
    reduce_pk<<<(NTOK*(size_t)DBC_N)/1024,256,0,stream>>>(pkpart, dbc);
  }
  // 4) delta = softplus(dbc[:,:64] @ dt_proj_w + b) -> bf16
  //    (f32 sgemm, 128x128 tile, TM=TN=8: halved LDS traffic)
  {
    dim3 grid(D_INNER/128, NTOK/128);           // (16,64)
    sgemm_softplus<<<grid,256,0,stream>>>(
        dbc, DBC_N, dt_proj_w, D_INNER, delta_bf, D_INNER, dt_proj_b);
  }
  // 5) chunked scan (NC=64, full-state: 2048 blocks -> 32 waves/CU);
  //    part2 writes y bf16 in-place over z (qbuf @0 over dead pkpart/xi_bf)
  {
    dim3 grid1((D_INNER/256)*NC*BATCH);           // 2048 blocks
    scan_part1<<<grid1,256,0,stream>>>(dbc, delta_bf, u_bf, A_log, qbuf, sumdl);
    scan_combine<<<(BATCH*(size_t)D_INNER*D_STATE)/256,256,0,stream>>>(qbuf, sumdl, A_log);
    scan_part2<<<grid1,256,0,stream>>>(dbc, delta_bf, u_bf, zybuf, qbuf, A_log, Dp);
  }
  // 6) preln = y @ out_proj_w  (MFMA, f32 out; preln @0 over dead qbuf)
  {
    dim3 grid(D_MODEL/128, NTOK/128);
    mfma_gemm<0><<<grid,256,0,stream>>>(D_INNER,
        zybuf, D_INNER, w_outT, D_INNER, preln, D_MODEL, nullptr);
  }
  // 7) LayerNorm: preln f32 -> out f32
  ln_kernel<<<NTOK,256,0,stream>>>(preln, out, ln_gamma, ln_beta);
}

// Round 14
// 534.495 us; speedup vs baseline: 1.1158x; 1.1158x over previous
//
#include <hip/hip_runtime.h>
#include <math.h>

#define D_MODEL 1024
#define D_STATE 32
#define D_CONV  4
#define D_INNER 2048
#define DT_RANK 64
#define BATCH   4
#define SEQ     2048
#define NTOK    (BATCH*SEQ)            // 8192 rows
#define DBC_N   (DT_RANK + 2*D_STATE)  // 128
#define NC      64                     // scan chunks
#define CL      (SEQ/NC)               // 32 steps per chunk
#define KSPLIT  4                      // split-K factor for dbc GEMM
#define LOG2E   1.4426950408889634f
#define LN2     0.6931471805599453f

typedef unsigned short u16;
typedef short bf16x8 __attribute__((ext_vector_type(8)));
typedef float f32x4  __attribute__((ext_vector_type(4)));
typedef u16   u16x8  __attribute__((ext_vector_type(8)));

__device__ __forceinline__ float bf2f(u16 u){
  return __uint_as_float(((unsigned)u) << 16);
}
__device__ __forceinline__ u16 f2bf(float f){   // round-to-nearest-even
  unsigned u = __float_as_uint(f);
  return (u16)((u + 0x7fffu + ((u >> 16) & 1u)) >> 16);
}
__device__ __forceinline__ float sigmoidf_(float x){ return 1.f/(1.f+__expf(-x)); }
// raw v_exp_f32: r = 2^x (1 instruction; __expf = mul + this)
__device__ __forceinline__ float exp2_fast(float x){
  float r;
  asm("v_exp_f32 %0, %1" : "=v"(r) : "v"(x));
  return r;
}
// raw v_log_f32: r = log2(x)
__device__ __forceinline__ float log2_fast(float x){
  float r;
  asm("v_log_f32 %0, %1" : "=v"(r) : "v"(x));
  return r;
}
// softplus via HW transcendentals only (no libm log1pf: R10-R12 showed the
// delta GEMM pinned at ~90us across 4 compute structures -- the shared
// epilogue was the suspect): ln(1+e^v) = log2(1+2^(v*log2e))*ln2.
__device__ __forceinline__ float softplus_fast(float v){
  if (v > 20.f) return v;
  return log2_fast(1.f + exp2_fast(v * LOG2E)) * LN2;
}

typedef __attribute__((address_space(3))) void       lds_v;
typedef const __attribute__((address_space(1))) void gl_v;
#define GLOAD_LDS16(g, l) \
  __builtin_amdgcn_global_load_lds((gl_v*)(g), (lds_v*)(l), 16, 0, 0)

// ---------------------------------------------------------------------------
// bf16 MFMA GEMM: C = A[M,K] @ W[K,N], A bf16 row-major [M][K], B = weight
// PRE-TRANSPOSED bf16 [N][K]. 128x128 tile, BK=64, 4 waves of 64x64.
// Staging via global_load_lds width=16 into LINEAR [128][64] LDS (32 KB).
// SWIZZLE (both-sides-or-neither): LDS[r][c'] holds logical 16B chunk
// c = c' ^ (r&7); staging fetches global chunk c_d ^ (r&7); reads XOR the
// same key -> all 8 bank-quads hit 2x per 16-lane group (2-way = free).
// ~810 TF on in_proj = at the m97-structure ceiling.
// Only used for K >= 512 shapes (K=64 delta GEMM is latency-bound here).
// MODES:
//  0: f32 store C1[row*ldc+col]                       (out_proj)
//  2: split in_proj, BOTH bf16: col<D_INNER -> (u16*)C1; else C2@col-2048
//  3: split-K partials: K arg = Kc; A,B advanced by kz*Kc;
//     store f32 at C1 + kz*NTOK*DBC_N                  (dbc)
// ---------------------------------------------------------------------------
template<int MODE>
__global__ __launch_bounds__(256)
void mfma_gemm(int K,
               const u16* __restrict__ A, int lda,
               const u16* __restrict__ B, int ldb,   // [N][K]
               void* __restrict__ C1, int ldc,
               u16*  __restrict__ C2)
{
  __shared__ u16 As[128*64];
  __shared__ u16 Bs[128*64];
  const int tid  = threadIdx.x;
  const int lane = tid & 63;
  const int wave = tid >> 6;
  const int wm = (wave>>1)*64, wn = (wave&1)*64;
  const int m0 = blockIdx.y*128, n0 = blockIdx.x*128;
  const size_t koff = (MODE==3) ? (size_t)blockIdx.z*K : 0;

  // staging: 4 gloads/tile; gload g covers rows 32g..32g+31.
  const int srow = tid >> 3;            // 0..31 row within 32-row group
  const int sch  = ((tid & 7) ^ (srow & 7)) * 8;   // swizzled source chunk

  const u16* Ag = A + (size_t)(m0 + srow)*lda + sch + koff;
  const u16* Bg = B + (size_t)(n0 + srow)*ldb + sch + koff;

  const int fr = lane & 15;         // fragment row within 16
  const int fq = lane >> 4;         // quad: k-chunk of 8
  const int rkey = (fr & 7);        // read-side XOR key (loop-invariant)
  f32x4 acc[4][4] = {};

  for (int k0=0; k0<K; k0+=64){
    #pragma unroll
    for (int g=0; g<4; ++g){
      GLOAD_LDS16(Ag + (size_t)(32*g)*lda + k0, &As[g*2048 + tid*8]);
      GLOAD_LDS16(Bg + (size_t)(32*g)*ldb + k0, &Bs[g*2048 + tid*8]);
    }
    __syncthreads();                 // drains vmcnt -> LDS tile ready

    #pragma unroll
    for (int ks=0; ks<2; ++ks){
      const int rc = ((ks*4 + fq) ^ rkey) * 8;   // swizzled read chunk
      bf16x8 af[4], bfr[4];
      #pragma unroll
      for (int i=0;i<4;i++){
        af[i]  = *(const bf16x8*)&As[(wm + i*16 + fr)*64 + rc];
        bfr[i] = *(const bf16x8*)&Bs[(wn + i*16 + fr)*64 + rc];
      }
      #pragma unroll
      for (int mi=0;mi<4;mi++)
        #pragma unroll
        for (int ni=0;ni<4;ni++)
          acc[mi][ni] = __builtin_amdgcn_mfma_f32_16x16x32_bf16(
              af[mi], bfr[ni], acc[mi][ni], 0, 0, 0);
    }
    __syncthreads();                 // all reads done before next overwrite
  }

  float* Cf = (float*)C1;
  if (MODE==3) Cf += (size_t)blockIdx.z*((size_t)NTOK*DBC_N);

  // C/D layout: row = fq*4 + r, col = fr  (m89-verified)
  const bool second = (MODE==2) && (n0 >= D_INNER);   // block-uniform
  #pragma unroll
  for (int mi=0;mi<4;mi++){
    #pragma unroll
    for (int ni=0;ni<4;ni++){
      int col = n0 + wn + ni*16 + fr;
      #pragma unroll
      for (int r=0;r<4;r++){
        int row = m0 + wm + mi*16 + fq*4 + r;
        float v = acc[mi][ni][r];
        if (MODE==0 || MODE==3){
          Cf[(size_t)row*ldc + col] = v;
        } else {  // MODE 2: dual bf16
          if (second) C2[(size_t)row*D_INNER + (col - D_INNER)] = f2bf(v);
          else        ((u16*)C1)[(size_t)row*D_INNER + col]     = f2bf(v);
        }
      }
    }
  }
}

// ---------------------------------------------------------------------------
// delta = softplus(dbc[:, :64] @ dt_proj_w + bias) -> bf16.
// f32 vector-ALU GEMM, 64x64 tile, BK=16, TM=TN=4 (R10 structure: best
// measured of 4 variants -- 90.0us @60% occupancy vs 92.5/96.5/164).
// Epilogue uses softplus_fast (HW exp2/log2, no libm log1pf) -- the one
// factor shared by all 4 equal-time variants, tested in isolation here.
// ---------------------------------------------------------------------------
__global__ __launch_bounds__(256)
void sgemm_softplus(const float* __restrict__ A, int lda,   // dbc [NTOK][128]
                    const float* __restrict__ B, int ldb,   // dt_proj_w [64][2048]
                    u16* __restrict__ C, int ldc,           // delta_bf
                    const float* __restrict__ bias)
{
  const int BM=64, BN=64, BK=16, TM=4, TN=4;
  __shared__ float As[BK][BM];
  __shared__ float Bs[BK][BN];
  const int tid  = threadIdx.x;
  const int brow = blockIdx.y, bcol = blockIdx.x;
  const int tcol = tid % (BN/TN);        // 0..15
  const int trow = tid / (BN/TN);        // 0..15

  const float* Ag = A + (size_t)brow*BM*lda;
  const float* Bg = B + (size_t)bcol*BN;

  const int arow = tid / (BK/4);         // 0..63
  const int acol = (tid % (BK/4))*4;     // 0,4,8,12
  const int brw  = tid / (BN/4);         // 0..15
  const int bcv  = (tid % (BN/4))*4;     // 0..60

  float acc[TM][TN] = {};

  for (int k0=0; k0<DT_RANK; k0+=BK){
    float4 av = *(const float4*)(Ag + (size_t)arow*lda + k0 + acol);
    float4 bv = *(const float4*)(Bg + (size_t)(k0+brw)*ldb + bcv);
    __syncthreads();
    As[acol+0][arow]=av.x; As[acol+1][arow]=av.y;
    As[acol+2][arow]=av.z; As[acol+3][arow]=av.w;
    *(float4*)&Bs[brw][bcv] = bv;
    __syncthreads();
    #pragma unroll
    for (int kk=0;kk<BK;kk++){
      float ra[TM], rb[TN];
      #pragma unroll
      for (int m=0;m<TM;m++) ra[m]=As[kk][trow*TM+m];
      #pragma unroll
      for (int n=0;n<TN;n++) rb[n]=Bs[kk][tcol*TN+n];
      #pragma unroll
      for (int m=0;m<TM;m++)
        #pragma unroll
        for (int n=0;n<TN;n++)
          acc[m][n] += ra[m]*rb[n];
    }
  }

  #pragma unroll
  for (int m=0;m<TM;m++){
    int row = brow*BM + trow*TM + m;
    ushort4 o;
    #pragma unroll
    for (int n=0;n<TN;n++){
      int col = bcol*BN + tcol*TN + n;
      float v = softplus_fast(acc[m][n] + bias[col]);
      ((u16*)&o)[n] = f2bf(v);
    }
    *(ushort4*)(C + (size_t)row*ldc + bcol*BN + tcol*TN) = o;
  }
}

// ---------------------------------------------------------------------------
// f32 -> bf16 elementwise (n multiple of 1024)
// ---------------------------------------------------------------------------
__global__ __launch_bounds__(256)
void cvt_f32_bf16(const float* __restrict__ in, u16* __restrict__ out)
{
  size_t i = (size_t)blockIdx.x*256 + threadIdx.x;
  float4 v = ((const float4*)in)[i];
  ushort4 o;
  o.x=f2bf(v.x); o.y=f2bf(v.y); o.z=f2bf(v.z); o.w=f2bf(v.w);
  ((ushort4*)out)[i] = o;
}

// ---------------------------------------------------------------------------
// f32 [R][C] -> bf16 [C][R] transpose+convert, 64x64 tiles, 256 threads.
// ---------------------------------------------------------------------------
__global__ __launch_bounds__(256)
void transpose_cvt(const float* __restrict__ in, u16* __restrict__ out,
                   int R, int C)
{
  __shared__ float tile[64][65];
  const int bc = blockIdx.x*64, br = blockIdx.y*64;
  const int tx = threadIdx.x & 63, ty = threadIdx.x >> 6;
  #pragma unroll
  for (int i=0;i<16;i++){
    int r = ty + i*4;
    tile[r][tx] = in[(size_t)(br+r)*C + bc+tx];
  }
  __syncthreads();
  #pragma unroll
  for (int i=0;i<16;i++){
    int r = ty + i*4;
    out[(size_t)(bc+r)*R + br+tx] = f2bf(tile[tx][r]);
  }
}

// ---------------------------------------------------------------------------
// reduce KSPLIT partials into dbc (float4-vectorized over NTOK*DBC_N).
// ---------------------------------------------------------------------------
__global__ __launch_bounds__(256)
void reduce_pk(const float* __restrict__ part, float* __restrict__ dbc)
{
  size_t i = (size_t)blockIdx.x*256 + threadIdx.x;   // float4 index
  const size_t stride4 = (size_t)NTOK*DBC_N/4;
  float4 s = ((const float4*)part)[i];
  #pragma unroll
  for (int z=1; z<KSPLIT; ++z){
    float4 v = ((const float4*)part)[z*stride4 + i];
    s.x+=v.x; s.y+=v.y; s.z+=v.z; s.w+=v.w;
  }
  ((float4*)dbc)[i] = s;
}

// ---------------------------------------------------------------------------
// Depthwise causal conv (K=4) + bias + SiLU. bf16 in -> bf16 out (u).
// Vectorized: each thread handles 8 consecutive channels (ushort8 loads).
// ---------------------------------------------------------------------------
__global__ __launch_bounds__(256)
void conv_silu_kernel(const u16* __restrict__ xi_bf,
                      const float* __restrict__ conv_w,
                      const float* __restrict__ conv_b,
                      u16* __restrict__ u_bf)
{
  size_t i8 = (size_t)blockIdx.x*256 + threadIdx.x;  // over NTOK*D_INNER/8
  size_t base = i8*8;
  int d0 = (int)(base % D_INNER);
  size_t bt = base / D_INNER;
  int t = (int)(bt % SEQ);
  size_t b = bt / SEQ;
  const u16* xi = xi_bf + b*(size_t)SEQ*D_INNER + d0;

  float accv[8];
  #pragma unroll
  for (int j=0;j<8;j++) accv[j] = conv_b[d0+j];
  float4 cw[8];
  #pragma unroll
  for (int j=0;j<8;j++) cw[j] = *(const float4*)(conv_w + (size_t)(d0+j)*D_CONV);

  #pragma unroll
  for (int k=0;k<D_CONV;k++){
    int tt = t + k - (D_CONV-1);
    if (tt >= 0){
      u16x8 v = *(const u16x8*)(xi + (size_t)tt*D_INNER);
      accv[0] += bf2f(v[0]) * ((const float*)&cw[0])[k];
      accv[1] += bf2f(v[1]) * ((const float*)&cw[1])[k];
      accv[2] += bf2f(v[2]) * ((const float*)&cw[2])[k];
      accv[3] += bf2f(v[3]) * ((const float*)&cw[3])[k];
      accv[4] += bf2f(v[4]) * ((const float*)&cw[4])[k];
      accv[5] += bf2f(v[5]) * ((const float*)&cw[5])[k];
      accv[6] += bf2f(v[6]) * ((const float*)&cw[6])[k];
      accv[7] += bf2f(v[7]) * ((const float*)&cw[7])[k];
    }
  }
  u16x8 o;
  #pragma unroll
  for (int j=0;j<8;j++){
    float r = accv[j] * sigmoidf_(accv[j]);
    o[j] = f2bf(r);
  }
  *(u16x8*)(u_bf + base) = o;
}

// ---------------------------------------------------------------------------
// Chunked selective scan, pass 1: lane = channel, h[32] in registers.
// (Full-state, NC=64, plain global B reads — R8's LDS staging was neutral-
// negative: kernel is ~17% HBM, redundant loads were free L1 broadcasts.)
// FAST PATH (runtime-verified): A_log = log(tile(arange(1..32))) ->
// A2[s] = A2[0]*(s+1), so exp(dl*A[s]) = E^(s+1): ONE v_exp per timestep.
// delta/u are bf16.
// ---------------------------------------------------------------------------
__global__ __launch_bounds__(256)
void scan_part1(const float* __restrict__ dbc,     // (NTOK,128)
                const u16*   __restrict__ delta,   // (NTOK,D_INNER) bf16
                const u16*   __restrict__ u,       // (NTOK,D_INNER) bf16
                const float* __restrict__ A_log,   // (D_INNER,32)
                float* __restrict__ q,             // (B,NC,D_INNER,32)
                float* __restrict__ sumdl_buf)     // (B,NC,D_INNER)
{
  const int ndg  = D_INNER/256;                 // 8
  const int dgrp = blockIdx.x % ndg;
  const int c    = (blockIdx.x / ndg) % NC;
  const int b    =  blockIdx.x / (ndg*NC);
  const int d    = dgrp*256 + threadIdx.x;

  const float* Ap = A_log + (size_t)d*D_STATE;
  const float base = -__expf(Ap[0]) * LOG2E;      // log2e folded into A
  bool fastp = true;
  #pragma unroll
  for (int s=1; s<D_STATE; ++s){
    float a2 = -__expf(Ap[s]) * LOG2E;
    float ideal = base * (float)(s+1);
    fastp = fastp && (fabsf(a2 - ideal) <= 1e-4f*fabsf(ideal));
  }

  const size_t tok0 = (size_t)b*SEQ + (size_t)c*CL;
  const u16*   dptr = delta + tok0*D_INNER + d;
  const u16*   uptr = u     + tok0*D_INNER + d;
  const float* dbcp = dbc   + tok0*DBC_N;

  float h[D_STATE] = {};
  float sumdl = 0.f;

  if (fastp){
    for (int t=0; t<CL; ++t){
      float dl = bf2f(dptr[(size_t)t*D_INNER]);
      float uu = bf2f(uptr[(size_t)t*D_INNER]);
      sumdl += dl;
      float w  = dl*uu;
      float E  = exp2_fast(dl*base);
      float E2 = E*E, E3 = E2*E, E4 = E2*E2;
      float P  = 1.f;
      const float4* B4 = (const float4*)(dbcp + (size_t)t*DBC_N + DT_RANK);
      #pragma unroll
      for (int g=0; g<8; ++g){
        float4 Bv = B4[g];
        float m0 = P*E, m1 = P*E2, m2 = P*E3, m3 = P*E4;
        h[4*g+0] = m0*h[4*g+0] + w*Bv.x;
        h[4*g+1] = m1*h[4*g+1] + w*Bv.y;
        h[4*g+2] = m2*h[4*g+2] + w*Bv.z;
        h[4*g+3] = m3*h[4*g+3] + w*Bv.w;
        P = m3;
      }
    }
  } else {
    float A2[D_STATE];
    #pragma unroll
    for (int g=0; g<8; ++g){
      float4 al = *(const float4*)(Ap + 4*g);
      A2[4*g+0] = -__expf(al.x)*LOG2E; A2[4*g+1] = -__expf(al.y)*LOG2E;
      A2[4*g+2] = -__expf(al.z)*LOG2E; A2[4*g+3] = -__expf(al.w)*LOG2E;
    }
    for (int t=0; t<CL; ++t){
      float dl = bf2f(dptr[(size_t)t*D_INNER]);
      float uu = bf2f(uptr[(size_t)t*D_INNER]);
      sumdl += dl;
      float w = dl*uu;
      const float4* B4 = (const float4*)(dbcp + (size_t)t*DBC_N + DT_RANK);
      #pragma unroll
      for (int g=0; g<8; ++g){
        float4 Bv = B4[g];
        h[4*g+0] = exp2_fast(dl*A2[4*g+0])*h[4*g+0] + w*Bv.x;
        h[4*g+1] = exp2_fast(dl*A2[4*g+1])*h[4*g+1] + w*Bv.y;
        h[4*g+2] = exp2_fast(dl*A2[4*g+2])*h[4*g+2] + w*Bv.z;
        h[4*g+3] = exp2_fast(dl*A2[4*g+3])*h[4*g+3] + w*Bv.w;
      }
    }
  }

  float* qp = q + (((size_t)b*NC + c)*D_INNER + d)*D_STATE;
  #pragma unroll
  for (int g=0; g<8; ++g)
    ((float4*)qp)[g] = make_float4(h[4*g+0],h[4*g+1],h[4*g+2],h[4*g+3]);
  sumdl_buf[((size_t)b*NC + c)*D_INNER + d] = sumdl;
}

// ---------------------------------------------------------------------------
// Pass 2: sequential combine across chunks, in-place on q.
// ---------------------------------------------------------------------------
__global__ __launch_bounds__(256)
void scan_combine(float* __restrict__ q,
                  const float* __restrict__ sumdl_buf,
                  const float* __restrict__ A_log)
{
  size_t idx = (size_t)blockIdx.x*256 + threadIdx.x;   // over B*D_INNER*32
  int s = (int)(idx % D_STATE);
  size_t dd = idx / D_STATE;
  int d = (int)(dd % D_INNER);
  int b = (int)(dd / D_INNER);

  const float As2 = -__expf(A_log[(size_t)d*D_STATE + s]) * LOG2E;
  float H = 0.f;
  for (int c=0; c<NC; ++c){
    size_t off = (((size_t)b*NC + c)*D_INNER + d)*D_STATE + s;
    float tmp = q[off];          // chunk-local end state
    q[off] = H;                  // h_in for chunk c
    H = exp2_fast(As2 * sumdl_buf[((size_t)b*NC + c)*D_INNER + d]) * H + tmp;
  }
}

// ---------------------------------------------------------------------------
// Pass 3: re-run recurrence from h_in; y = sum_s h*C, fused D-skip + z-gate.
// y accumulated in FOUR independent partials (chain depth 32 -> 10; the
// compiler cannot reassociate without fast-math).
// z bf16 read, y bf16 written IN-PLACE (same slot, same thread -> race-free).
// ---------------------------------------------------------------------------
__global__ __launch_bounds__(256)
void scan_part2(const float* __restrict__ dbc,     // (NTOK,128)
                const u16*   __restrict__ delta,   // (NTOK,D_INNER) bf16
                const u16*   __restrict__ u,       // bf16
                u16*         __restrict__ zy,      // in: z bf16, out: y bf16
                const float* __restrict__ q,       // h_in per chunk
                const float* __restrict__ A_log,
                const float* __restrict__ Dp)
{
  const int ndg  = D_INNER/256;
  const int dgrp = blockIdx.x % ndg;
  const int c    = (blockIdx.x / ndg) % NC;
  const int b    =  blockIdx.x / (ndg*NC);
  const int d    = dgrp*256 + threadIdx.x;

  const float* Ap = A_log + (size_t)d*D_STATE;
  const float base = -__expf(Ap[0]) * LOG2E;
  bool fastp = true;
  #pragma unroll
  for (int s=1; s<D_STATE; ++s){
    float a2 = -__expf(Ap[s]) * LOG2E;
    float ideal = base * (float)(s+1);
    fastp = fastp && (fabsf(a2 - ideal) <= 1e-4f*fabsf(ideal));
  }

  float h[D_STATE];
  const float* qp = q + (((size_t)b*NC + c)*D_INNER + d)*D_STATE;
  #pragma unroll
  for (int g=0; g<8; ++g){
    float4 hv = ((const float4*)qp)[g];
    h[4*g+0]=hv.x; h[4*g+1]=hv.y; h[4*g+2]=hv.z; h[4*g+3]=hv.w;
  }
  const float Dd = Dp[d];

  const size_t tok0 = (size_t)b*SEQ + (size_t)c*CL;
  const u16*   dptr = delta + tok0*D_INNER + d;
  const u16*   uptr = u     + tok0*D_INNER + d;
  u16*         zp   = zy    + tok0*D_INNER + d;
  const float* dbcp = dbc   + tok0*DBC_N;

  if (fastp){
    for (int t=0; t<CL; ++t){
      float dl = bf2f(dptr[(size_t)t*D_INNER]);
      float uu = bf2f(uptr[(size_t)t*D_INNER]);
      float zz = bf2f(zp[(size_t)t*D_INNER]);
      float w  = dl*uu;
      float E  = exp2_fast(dl*base);
      float E2 = E*E, E3 = E2*E, E4 = E2*E2;
      float P  = 1.f;
      const float4* B4 = (const float4*)(dbcp + (size_t)t*DBC_N + DT_RANK);
      const float4* C4 = B4 + 8;
      float ya0 = 0.f, ya1 = 0.f, ya2 = 0.f, ya3 = 0.f;
      #pragma unroll
      for (int g=0; g<8; ++g){
        float4 Bv = B4[g];
        float4 Cv = C4[g];
        float m0 = P*E, m1 = P*E2, m2 = P*E3, m3 = P*E4;
        h[4*g+0] = m0*h[4*g+0] + w*Bv.x;  ya0 += h[4*g+0]*Cv.x;
        h[4*g+1] = m1*h[4*g+1] + w*Bv.y;  ya1 += h[4*g+1]*Cv.y;
        h[4*g+2] = m2*h[4*g+2] + w*Bv.z;  ya2 += h[4*g+2]*Cv.z;
        h[4*g+3] = m3*h[4*g+3] + w*Bv.w;  ya3 += h[4*g+3]*Cv.w;
        P = m3;
      }
      float y = (ya0 + ya1) + (ya2 + ya3);
      zp[(size_t)t*D_INNER] = f2bf((y + uu*Dd) * (zz * sigmoidf_(zz)));
    }
  } else {
    float A2[D_STATE];
    #pragma unroll
    for (int g=0; g<8; ++g){
      float4 al = *(const float4*)(Ap + 4*g);
      A2[4*g+0] = -__expf(al.x)*LOG2E; A2[4*g+1] = -__expf(al.y)*LOG2E;
      A2[4*g+2] = -__expf(al.z)*LOG2E; A2[4*g+3] = -__expf(al.w)*LOG2E;
    }
    for (int t=0; t<CL; ++t){
      float dl = bf2f(dptr[(size_t)t*D_INNER]);
      float uu = bf2f(uptr[(size_t)t*D_INNER]);
      float zz = bf2f(zp[(size_t)t*D_INNER]);
      float w  = dl*uu;
      const float4* B4 = (const float4*)(dbcp + (size_t)t*DBC_N + DT_RANK);
      const float4* C4 = B4 + 8;
      float ya0 = 0.f, ya1 = 0.f, ya2 = 0.f, ya3 = 0.f;
      #pragma unroll
      for (int g=0; g<8; ++g){
        float4 Bv = B4[g];
        float4 Cv = C4[g];
        h[4*g+0] = exp2_fast(dl*A2[4*g+0])*h[4*g+0] + w*Bv.x;  ya0 += h[4*g+0]*Cv.x;
        h[4*g+1] = exp2_fast(dl*A2[4*g+1])*h[4*g+1] + w*Bv.y;  ya1 += h[4*g+1]*Cv.y;
        h[4*g+2] = exp2_fast(dl*A2[4*g+2])*h[4*g+2] + w*Bv.z;  ya2 += h[4*g+2]*Cv.z;
        h[4*g+3] = exp2_fast(dl*A2[4*g+3])*h[4*g+3] + w*Bv.w;  ya3 += h[4*g+3]*Cv.w;
      }
      float y = (ya0 + ya1) + (ya2 + ya3);
      zp[(size_t)t*D_INNER] = f2bf((y + uu*Dd) * (zz * sigmoidf_(zz)));
    }
  }
}

// ---------------------------------------------------------------------------
// LayerNorm over last dim (1024): read f32 pre-LN, write f32 output.
// float4 loads/stores: thread t owns cols [4t, 4t+4).
// ---------------------------------------------------------------------------
__global__ __launch_bounds__(256)
void ln_kernel(const float* __restrict__ in,
               float* __restrict__ out,
               const float* __restrict__ gamma,
               const float* __restrict__ beta)
{
  const int row = blockIdx.x;
  const float* p = in + (size_t)row*D_MODEL;
  float* q = out + (size_t)row*D_MODEL;
  float4 v = ((const float4*)p)[threadIdx.x];
  float s  = v.x+v.y+v.z+v.w;
  float ss = v.x*v.x+v.y*v.y+v.z*v.z+v.w*v.w;
  #pragma unroll
  for (int off=32; off; off>>=1){
    s  += __shfl_xor(s,  off, 64);
    ss += __shfl_xor(ss, off, 64);
  }
  __shared__ float sw[4], ssw[4];
  const int wid = threadIdx.x >> 6;
  if ((threadIdx.x & 63) == 0){ sw[wid]=s; ssw[wid]=ss; }
  __syncthreads();
  s  = sw[0]+sw[1]+sw[2]+sw[3];
  ss = ssw[0]+ssw[1]+ssw[2]+ssw[3];
  const float mu  = s * (1.f/D_MODEL);
  const float var = ss * (1.f/D_MODEL) - mu*mu;
  const float inv = rsqrtf(var + 1e-5f);
  float4 gm = ((const float4*)gamma)[threadIdx.x];
  float4 bt = ((const float4*)beta )[threadIdx.x];
  float4 o;
  o.x = (v.x-mu)*inv*gm.x + bt.x;
  o.y = (v.y-mu)*inv*gm.y + bt.y;
  o.z = (v.z-mu)*inv*gm.z + bt.z;
  o.w = (v.w-mu)*inv*gm.w + bt.w;
  ((float4*)q)[threadIdx.x] = o;
}

// ---------------------------------------------------------------------------
extern "C" void kernel_launch(void* const* d_in, const int* in_sizes, int n_in,
                              void* d_out, int out_size, void* d_ws, size_t ws_size,
                              hipStream_t stream)
{
  const float* x          = (const float*)d_in[0];   // (4,2048,1024) f32
  const float* in_proj_w  = (const float*)d_in[1];   // (1024,4096)
  const float* conv_w     = (const float*)d_in[2];   // (2048,4)
  const float* conv_b     = (const float*)d_in[3];   // (2048,)
  const float* x_proj_w   = (const float*)d_in[4];   // (2048,128)
  const float* dt_proj_w  = (const float*)d_in[5];   // (64,2048)
  const float* dt_proj_b  = (const float*)d_in[6];   // (2048,)
  const float* A_log      = (const float*)d_in[7];   // (2048,32)
  const float* Dp         = (const float*)d_in[8];   // (2048,)
  const float* out_proj_w = (const float*)d_in[9];   // (2048,1024)
  const float* ln_gamma   = (const float*)d_in[10];  // (1024,)
  const float* ln_beta    = (const float*)d_in[11];  // (1024,)
  float* out = (float*)d_out;                        // (4,2048,1024) f32 OUTPUT

  // workspace (byte offsets), ws_size = 256 MiB:
  //   @0     x_bf bf16 16M (steps 0-1) -> pkpart f32 16M (step 3)
  //          -> qbuf f32 64M (step 5, covers 0-64M; pkpart+xi_bf dead)
  //          -> preln f32 32M (steps 6-7; qbuf dead)
  //   @32M   xi_bf bf16 32M (steps 1-2)
  //   @64M   u_bf bf16 32M (steps 2,3,5)
  //   @96M   zybuf bf16 32M (steps 1,5,6)
  //   @128M  delta_bf bf16 32M (steps 4,5)
  //   @160M  dbc f32 4M ; @165M sumdl 2M (NC=64)
  //   @198M  w_inT 8M ; @206M w_outT 4M ; @210M x_projT
  char* ws = (char*)d_ws;
  u16*   x_bf    = (u16*)  (ws + 0);
  float* pkpart  = (float*)(ws + 0);
  float* qbuf    = (float*)(ws + 0);
  float* preln   = (float*)(ws + 0);
  u16*   xi_bf   = (u16*)  (ws + (size_t) 33554432);
  u16*   u_bf    = (u16*)  (ws + (size_t) 67108864);
  u16*   zybuf   = (u16*)  (ws + (size_t)100663296);
  u16*   delta_bf= (u16*)  (ws + (size_t)134217728);
  float* dbc     = (float*)(ws + (size_t)167772160);
  float* sumdl   = (float*)(ws + (size_t)173015040);
  u16*   w_inT   = (u16*)  (ws + (size_t)207618048);
  u16*   w_outT  = (u16*)  (ws + (size_t)216006656);
  u16*   x_projT = (u16*)  (ws + (size_t)220200960);

  // 0) dtype prep: x -> bf16; weights -> bf16 transposed [N][K]
  cvt_f32_bf16<<<(NTOK*(size_t)D_MODEL)/1024, 256, 0, stream>>>(x, x_bf);
  { dim3 g(4096/64, 1024/64); transpose_cvt<<<g,256,0,stream>>>(in_proj_w,  w_inT,  1024, 4096); }
  { dim3 g(1024/64, 2048/64); transpose_cvt<<<g,256,0,stream>>>(out_proj_w, w_outT, 2048, 1024); }
  { dim3 g( 128/64, 2048/64); transpose_cvt<<<g,256,0,stream>>>(x_proj_w,   x_projT, 2048, 128); }

  // 1) merged in_proj: [xi | z] = x @ in_proj_w  (MFMA, dual bf16 epilogue)
  {
    dim3 grid(2*D_INNER/128, NTOK/128);
    mfma_gemm<2><<<grid,256,0,stream>>>(D_MODEL,
        x_bf, D_MODEL, w_inT, D_MODEL, xi_bf, 0, zybuf);
  }
  // 2) u = silu(conv(xi) + conv_b)   bf16 -> bf16  (xi_bf dead after)
  conv_silu_kernel<<<(NTOK*(size_t)D_INNER)/2048,256,0,stream>>>(
      xi_bf, conv_w, conv_b, u_bf);

  // 3) dbc = u_bf @ x_proj_w  (MFMA split-K over 4, partials @0, x_bf dead)
  {
    dim3 grid(DBC_N/128, NTOK/128, KSPLIT);     // (1,64,4)
    mfma_gemm<3><<<grid,256,0,stream>>>(D_INNER/KSPLIT,
        u_bf, D_INNER, x_projT, D_INNER, pkpart, DBC_N, nullptr);
    reduce_pk<<<(NTOK*(size_t)DBC_N)/1024,256,0,stream>>>(pkpart, dbc);
  }
  // 4) delta = softplus(dbc[:,:64] @ dt_proj_w + b) -> bf16
  //    (f32 sgemm 64x64/BK=16 + HW exp2/log2 softplus)
  {
    dim3 grid(D_INNER/64, NTOK/64);             // (32,128)
    sgemm_softplus<<<grid,256,0,stream>>>(
        dbc, DBC_N, dt_proj_w, D_INNER, delta_bf, D_INNER, dt_proj_b);
  }
  // 5) chunked scan (NC=64, full-state: 2048 blocks -> 32 waves/CU);
  //    part2 writes y bf16 in-place over z (qbuf @0 over dead pkpart/xi_bf)
  {
    dim3 grid1((D_INNER/256)*NC*BATCH);           // 2048 blocks
    scan_part1<<<grid1,256,0,stream>>>(dbc, delta_bf, u_bf, A_log, qbuf, sumdl);
    scan_combine<<<(BATCH*(size_t)D_INNER*D_STATE)/256,256,0,stream>>>(qbuf, sumdl, A_log);
    scan_part2<<<grid1,256,0,stream>>>(dbc, delta_bf, u_bf, zybuf, qbuf, A_log, Dp);
  }
  // 6) preln = y @ out_proj_w  (MFMA, f32 out; preln @0 over dead qbuf)
  {
    dim3 grid(D_MODEL/128, NTOK/128);
    mfma_gemm<0><<<grid,256,0,stream>>>(D_INNER,
        zybuf, D_INNER, w_outT, D_INNER, preln, D_MODEL, nullptr);
  }
  // 7) LayerNorm: preln f32 -> out f32
  ln_kernel<<<NTOK,256,0,stream>>>(preln, out, ln_gamma, ln_beta);
}